// Round 4
// baseline (236.759 us; speedup 1.0000x reference)
//
#include <hip/hip_runtime.h>
#include <math.h>

// Problem constants
#define B_    8
#define C_    192
#define N_    3136          // H*W
#define K_    9
#define C2_   384
#define OUT_  192
#define M_    (B_ * N_)     // 25088 rows
#define EPS_  1e-5f

typedef __bf16 bf16;
typedef __bf16 bf16x8 __attribute__((ext_vector_type(8)));
typedef float  f32x4  __attribute__((ext_vector_type(4)));

__device__ __forceinline__ float gelu_f(float x) {
    return 0.5f * x * (1.0f + erff(x * 0.70710678118654752440f));
}

// async global->LDS, 16B per lane; lds base must be wave-uniform
__device__ __forceinline__ void gl_lds16(const void* g, void* l) {
    __builtin_amdgcn_global_load_lds(
        (const __attribute__((address_space(1))) unsigned int*)g,
        (__attribute__((address_space(3))) unsigned int*)l, 16, 0, 0);
}

// Swizzled LDS tile layout: tile is [rows][64] bf16, stored as 16B chunks.
// chunk(r, c8) lives at element offset (r*8 + (c8 ^ (r&7))) * 8.
// Fragment reads (16 lanes, fixed c8, rows r0..r0+15) then hit all 32 banks
// exactly 2-way (free on CDNA4), instead of 8/16-way with linear layout.
__device__ __forceinline__ int sw_off(int r, int c8) {
    return (r * 8 + (c8 ^ (r & 7))) * 8;
}

// ---------------------------------------------------------------------------
// k_pre: z<8 -> transpose x fp32 [B,C,N] -> xt bf16 [B,N,C]
//        z==8 -> cast+permute w1 -> w1p, cast w2 -> w2b, zero stats
// grid (49, 6, 9), block 256
__global__ __launch_bounds__(256) void k_pre(const float* __restrict__ x,
                                             bf16* __restrict__ xt,
                                             const float* __restrict__ w1,
                                             const float* __restrict__ w2,
                                             bf16* __restrict__ w1p,
                                             bf16* __restrict__ w2b,
                                             float* __restrict__ stats) {
    if (blockIdx.z == 8) {
        const int bid = blockIdx.y * 49 + blockIdx.x;        // 0..293
        #pragma unroll
        for (int t = 0; t < 2; ++t) {
            const int idx = bid * 512 + t * 256 + threadIdx.x;
            if (idx < C2_ * C2_) {
                const int o  = idx / C2_;
                const int cc = idx - o * C2_;
                const int src = (cc < C_) ? (2 * cc) : (2 * (cc - C_) + 1);
                w1p[idx] = (bf16)w1[o * C2_ + src];
            }
            if (idx < OUT_ * C2_) w2b[idx] = (bf16)w2[idx];
            if (idx < 1152) stats[idx] = 0.f;   // p1s[384] p1q[384] p2s[192] p2q[192]
        }
        return;
    }
    __shared__ float T[32][65];
    const int b  = blockIdx.z;
    const int c0 = blockIdx.y * 32;
    const int n0 = blockIdx.x * 64;
    const int tid = threadIdx.x;
    {
        const int nl = tid & 63;
        const int cl = tid >> 6;
        #pragma unroll
        for (int r = 0; r < 8; ++r) {
            const int c = cl + r * 4;
            T[c][nl] = x[((size_t)b * C_ + (c0 + c)) * N_ + n0 + nl];
        }
    }
    __syncthreads();
    {
        const int cl = tid & 31;
        const int nl = tid >> 5;
        #pragma unroll
        for (int r = 0; r < 8; ++r) {
            const int n = nl + r * 8;
            xt[((size_t)b * N_ + n0 + n) * C_ + c0 + cl] = (bf16)T[cl][n];
        }
    }
}

// ---------------------------------------------------------------------------
// Feats (diff half): d[node][c] = max_k( xt[j_k][c] - xt[i_k][c] )
// grid M, block 192
__global__ __launch_bounds__(192) void k_feats(const bf16* __restrict__ xt,
                                               const int* __restrict__ eidx,
                                               bf16* __restrict__ dbuf) {
    const int node = blockIdx.x;
    const int b = node / N_;
    const int c = threadIdx.x;
    const int* e0 = eidx + (size_t)node * K_;
    const int* e1 = e0 + (size_t)M_ * K_;
    const bf16* xb = xt + (size_t)b * N_ * C_;
    float mx = -1e30f;
    #pragma unroll
    for (int k = 0; k < K_; ++k) {
        const int j = e0[k];
        const int i = e1[k];
        mx = fmaxf(mx, (float)xb[(size_t)j * C_ + c] - (float)xb[(size_t)i * C_ + c]);
    }
    dbuf[(size_t)node * C_ + c] = (bf16)mx;
}

// ---------------------------------------------------------------------------
// GEMM1: h1[m,o] = sum_c [X|D][m,c] * w1p[o,c] + b1[o] -> bf16, fused stats
// 128x128 tile, BK=64, swizzled LDS, 4 waves x (4x4) 16x16x32 frags
// grid (196, 3), block 256
__global__ __launch_bounds__(256) void k_gemm1(const bf16* __restrict__ X,
                                               const bf16* __restrict__ D,
                                               const bf16* __restrict__ Wp,
                                               const float* __restrict__ bias,
                                               bf16* __restrict__ H1,
                                               float* __restrict__ psum,
                                               float* __restrict__ psq) {
    __shared__ bf16 As[128 * 64];
    __shared__ bf16 Bs[128 * 64];
    const int tid  = threadIdx.x;
    const int lane = tid & 63;
    const int wv   = tid >> 6;
    const int l16  = lane & 15;
    const int quad = lane >> 4;
    const int m0   = blockIdx.x * 128;
    const int n0   = blockIdx.y * 128;
    const int wm   = (wv & 1) * 64;
    const int wn   = (wv >> 1) * 64;

    f32x4 acc[4][4] = {};

    for (int kk = 0; kk < C2_; kk += 64) {
        __syncthreads();
        const bf16* asrc = (kk < C_) ? X : D;
        const int   acol = (kk < C_) ? kk : (kk - C_);
        // wave stages rows wv*32..+31 of both tiles: chunks [wv*256, wv*256+256)
        #pragma unroll
        for (int i = 0; i < 4; ++i) {
            const int qb = wv * 256 + i * 64;          // wave-uniform chunk base
            const int q  = qb + lane;
            const int r  = q >> 3;
            const int c8 = (q & 7) ^ (r & 7);          // global chunk for this slot
            gl_lds16(asrc + (size_t)(m0 + r) * C_ + acol + c8 * 8, &As[qb * 8]);
            gl_lds16(Wp   + (size_t)(n0 + r) * C2_ + kk  + c8 * 8, &Bs[qb * 8]);
        }
        __syncthreads();
        #pragma unroll
        for (int ks = 0; ks < 2; ++ks) {
            bf16x8 af[4], bfr[4];
            #pragma unroll
            for (int f = 0; f < 4; ++f) {
                af[f]  = *(const bf16x8*)&As[sw_off(wm + f * 16 + l16, ks * 4 + quad)];
                bfr[f] = *(const bf16x8*)&Bs[sw_off(wn + f * 16 + l16, ks * 4 + quad)];
            }
            #pragma unroll
            for (int mf = 0; mf < 4; ++mf)
                #pragma unroll
                for (int nf = 0; nf < 4; ++nf)
                    acc[mf][nf] = __builtin_amdgcn_mfma_f32_16x16x32_bf16(
                        af[mf], bfr[nf], acc[mf][nf], 0, 0, 0);
        }
    }

    // epilogue: bias, bf16 store, fused per-column stats
    #pragma unroll
    for (int nf = 0; nf < 4; ++nf) {
        const int col = n0 + wn + nf * 16 + l16;
        const float bv = bias[col];
        float s = 0.f, q = 0.f;
        #pragma unroll
        for (int mf = 0; mf < 4; ++mf) {
            #pragma unroll
            for (int r = 0; r < 4; ++r) {
                const float v = acc[mf][nf][r] + bv;
                s += v; q += v * v;
                H1[(size_t)(m0 + wm + mf * 16 + quad * 4 + r) * C2_ + col] = (bf16)v;
            }
        }
        s += __shfl_xor(s, 16); s += __shfl_xor(s, 32);
        q += __shfl_xor(q, 16); q += __shfl_xor(q, 32);
        if (quad == 0) { atomicAdd(&psum[col], s); atomicAdd(&psq[col], q); }
    }
}

// ---------------------------------------------------------------------------
// Activation with folded BN1 finalize: a1 = bf16(gelu(h1*sc + sh))
// grid 4704, block 256, 8 elems/thread
__global__ __launch_bounds__(256) void k_act(const bf16* __restrict__ H1,
                                             const float* __restrict__ p1s,
                                             const float* __restrict__ p1q,
                                             const float* __restrict__ g,
                                             const float* __restrict__ beta,
                                             bf16* __restrict__ A1) {
    const size_t i8 = ((size_t)blockIdx.x * 256 + threadIdx.x) * 8;
    const int c0 = (int)(i8 % C2_);
    const bf16x8 v = *(const bf16x8*)&H1[i8];
    bf16x8 o;
    #pragma unroll
    for (int j = 0; j < 8; ++j) {
        const int c = c0 + j;
        const float mean = p1s[c] * (1.0f / (float)M_);
        const float var  = p1q[c] * (1.0f / (float)M_) - mean * mean;
        const float inv  = rsqrtf(var + EPS_);
        const float scl  = g[c] * inv;
        const float sft  = beta[c] - mean * scl;
        o[j] = (bf16)gelu_f(fmaf((float)v[j], scl, sft));
    }
    *(bf16x8*)&A1[i8] = o;
}

// ---------------------------------------------------------------------------
// GEMM2: h2[m,o] = sum_c a1[m,c]*w2[o,c] + b2[o] -> bf16, fused stats
// 128x64 tile, BK=64, swizzled LDS, 4 waves x (4x2) frags
// grid (196, 3), block 256
__global__ __launch_bounds__(256) void k_gemm2(const bf16* __restrict__ A1,
                                               const bf16* __restrict__ W2,
                                               const float* __restrict__ bias,
                                               bf16* __restrict__ H2,
                                               float* __restrict__ psum,
                                               float* __restrict__ psq) {
    __shared__ bf16 As[128 * 64];
    __shared__ bf16 Bs[64 * 64];
    const int tid  = threadIdx.x;
    const int lane = tid & 63;
    const int wv   = tid >> 6;
    const int l16  = lane & 15;
    const int quad = lane >> 4;
    const int m0   = blockIdx.x * 128;
    const int n0   = blockIdx.y * 64;
    const int wm   = (wv & 1) * 64;
    const int wn   = (wv >> 1) * 32;

    f32x4 acc[4][2] = {};

    for (int kk = 0; kk < C2_; kk += 64) {
        __syncthreads();
        #pragma unroll
        for (int i = 0; i < 4; ++i) {
            const int qb = wv * 256 + i * 64;
            const int q  = qb + lane;
            const int r  = q >> 3;
            const int c8 = (q & 7) ^ (r & 7);
            gl_lds16(A1 + (size_t)(m0 + r) * C2_ + kk + c8 * 8, &As[qb * 8]);
        }
        #pragma unroll
        for (int i = 0; i < 2; ++i) {
            const int qb = wv * 128 + i * 64;
            const int q  = qb + lane;
            const int r  = q >> 3;
            const int c8 = (q & 7) ^ (r & 7);
            gl_lds16(W2 + (size_t)(n0 + r) * C2_ + kk + c8 * 8, &Bs[qb * 8]);
        }
        __syncthreads();
        #pragma unroll
        for (int ks = 0; ks < 2; ++ks) {
            bf16x8 af[4], bfr[2];
            #pragma unroll
            for (int f = 0; f < 4; ++f)
                af[f] = *(const bf16x8*)&As[sw_off(wm + f * 16 + l16, ks * 4 + quad)];
            #pragma unroll
            for (int f = 0; f < 2; ++f)
                bfr[f] = *(const bf16x8*)&Bs[sw_off(wn + f * 16 + l16, ks * 4 + quad)];
            #pragma unroll
            for (int mf = 0; mf < 4; ++mf)
                #pragma unroll
                for (int nf = 0; nf < 2; ++nf)
                    acc[mf][nf] = __builtin_amdgcn_mfma_f32_16x16x32_bf16(
                        af[mf], bfr[nf], acc[mf][nf], 0, 0, 0);
        }
    }

    #pragma unroll
    for (int nf = 0; nf < 2; ++nf) {
        const int col = n0 + wn + nf * 16 + l16;
        const float bv = bias[col];
        float s = 0.f, q = 0.f;
        #pragma unroll
        for (int mf = 0; mf < 4; ++mf) {
            #pragma unroll
            for (int r = 0; r < 4; ++r) {
                const float v = acc[mf][nf][r] + bv;
                s += v; q += v * v;
                H2[(size_t)(m0 + wm + mf * 16 + quad * 4 + r) * OUT_ + col] = (bf16)v;
            }
        }
        s += __shfl_xor(s, 16); s += __shfl_xor(s, 32);
        q += __shfl_xor(q, 16); q += __shfl_xor(q, 32);
        if (quad == 0) { atomicAdd(&psum[col], s); atomicAdd(&psq[col], q); }
    }
}

// ---------------------------------------------------------------------------
// Output with folded BN2 finalize: BN2+GELU + transpose [M,OUT] bf16 -> [B,OUT,N] fp32
// grid (N/64, OUT/32, B), block 256
__global__ __launch_bounds__(256) void k_out(const bf16* __restrict__ H2,
                                             const float* __restrict__ p2s,
                                             const float* __restrict__ p2q,
                                             const float* __restrict__ g,
                                             const float* __restrict__ beta,
                                             float* __restrict__ out) {
    __shared__ float T[64][33];
    const int b  = blockIdx.z;
    const int o0 = blockIdx.y * 32;
    const int n0 = blockIdx.x * 64;
    const int tid = threadIdx.x;
    {
        const int ol = tid & 31;
        const int nl = tid >> 5;
        const int o  = o0 + ol;
        const float mean  = p2s[o] * (1.0f / (float)M_);
        const float var   = p2q[o] * (1.0f / (float)M_) - mean * mean;
        const float inv   = rsqrtf(var + EPS_);
        const float scale = g[o] * inv;
        const float shift = beta[o] - mean * scale;
        #pragma unroll
        for (int r = 0; r < 8; ++r) {
            const int n = nl + r * 8;
            const float v = (float)H2[((size_t)b * N_ + n0 + n) * OUT_ + o];
            T[n][ol] = gelu_f(fmaf(v, scale, shift));
        }
    }
    __syncthreads();
    {
        const int nl = tid & 63;
        const int ol = tid >> 6;
        #pragma unroll
        for (int r = 0; r < 8; ++r) {
            const int o = ol + r * 4;
            out[((size_t)b * OUT_ + o0 + o) * N_ + n0 + nl] = T[nl][o];
        }
    }
}

// ---------------------------------------------------------------------------
extern "C" void kernel_launch(void* const* d_in, const int* in_sizes, int n_in,
                              void* d_out, int out_size, void* d_ws, size_t ws_size,
                              hipStream_t stream) {
    const float* x     = (const float*)d_in[0];
    const int*   eidx  = (const int*)  d_in[1];
    const float* w1    = (const float*)d_in[2];
    const float* b1    = (const float*)d_in[3];
    const float* g1    = (const float*)d_in[4];
    const float* beta1 = (const float*)d_in[5];
    const float* w2    = (const float*)d_in[6];
    const float* b2    = (const float*)d_in[7];
    const float* g2    = (const float*)d_in[8];
    const float* beta2 = (const float*)d_in[9];
    float* out = (float*)d_out;

    char* ws = (char*)d_ws;
    size_t off = 0;
    bf16*  xt    = (bf16*)(ws + off); off += (size_t)M_ * C_  * sizeof(bf16);
    bf16*  dbuf  = (bf16*)(ws + off); off += (size_t)M_ * C_  * sizeof(bf16);
    bf16*  h1    = (bf16*)(ws + off); off += (size_t)M_ * C2_ * sizeof(bf16);
    bf16*  a1    = (bf16*)(ws + off); off += (size_t)M_ * C2_ * sizeof(bf16);
    bf16*  h2    = (bf16*)(ws + off); off += (size_t)M_ * OUT_ * sizeof(bf16);
    bf16*  w1p   = (bf16*)(ws + off); off += (size_t)C2_ * C2_ * sizeof(bf16);
    bf16*  w2b   = (bf16*)(ws + off); off += (size_t)OUT_ * C2_ * sizeof(bf16);
    float* stats = (float*)(ws + off); off += 1152 * sizeof(float);
    float* p1s = stats;        // 384
    float* p1q = stats + 384;  // 384
    float* p2s = stats + 768;  // 192
    float* p2q = stats + 960;  // 192

    k_pre<<<dim3(N_ / 64, C_ / 32, B_ + 1), 256, 0, stream>>>(x, xt, w1, w2, w1p, w2b, stats);
    k_feats<<<M_, 192, 0, stream>>>(xt, eidx, dbuf);
    k_gemm1<<<dim3(M_ / 128, C2_ / 128), 256, 0, stream>>>(xt, dbuf, w1p, b1, h1, p1s, p1q);
    k_act<<<4704, 256, 0, stream>>>(h1, p1s, p1q, g1, beta1, a1);
    k_gemm2<<<dim3(M_ / 128, OUT_ / 64), 256, 0, stream>>>(a1, w2b, b2, h2, p2s, p2q);
    k_out<<<dim3(N_ / 64, OUT_ / 32, B_), 256, 0, stream>>>(h2, p2s, p2q, g2, beta2, out);
}

// Round 5
// 178.243 us; speedup vs baseline: 1.3283x; 1.3283x over previous
//
#include <hip/hip_runtime.h>
#include <math.h>

// Problem constants
#define B_    8
#define C_    192
#define N_    3136          // H*W
#define K_    9
#define C2_   384
#define OUT_  192
#define M_    (B_ * N_)     // 25088 rows
#define EPS_  1e-5f

typedef __bf16 bf16;
typedef __bf16 bf16x8 __attribute__((ext_vector_type(8)));
typedef float  f32x4  __attribute__((ext_vector_type(4)));

__device__ __forceinline__ float gelu_f(float x) {
    return 0.5f * x * (1.0f + erff(x * 0.70710678118654752440f));
}

// async global->LDS, 16B per lane; lds base must be wave-uniform
__device__ __forceinline__ void gl_lds16(const void* g, void* l) {
    __builtin_amdgcn_global_load_lds(
        (const __attribute__((address_space(1))) unsigned int*)g,
        (__attribute__((address_space(3))) unsigned int*)l, 16, 0, 0);
}

// Swizzled LDS tile layout: tile is [rows][64] bf16, stored as 16B chunks.
// chunk(r, c8) lives at element offset (r*8 + (c8 ^ (r&7))) * 8.
__device__ __forceinline__ int sw_off(int r, int c8) {
    return (r * 8 + (c8 ^ (r & 7))) * 8;
}

// ---------------------------------------------------------------------------
// k_pre: z<8 -> transpose x fp32 [B,C,N] -> xt bf16 [B,N,C]
//        z==8 -> cast+permute w1 -> w1p, cast w2 -> w2b, zero stats
// grid (49, 6, 9), block 256
__global__ __launch_bounds__(256) void k_pre(const float* __restrict__ x,
                                             bf16* __restrict__ xt,
                                             const float* __restrict__ w1,
                                             const float* __restrict__ w2,
                                             bf16* __restrict__ w1p,
                                             bf16* __restrict__ w2b,
                                             float* __restrict__ stats) {
    if (blockIdx.z == 8) {
        const int bid = blockIdx.y * 49 + blockIdx.x;        // 0..293
        #pragma unroll
        for (int t = 0; t < 2; ++t) {
            const int idx = bid * 512 + t * 256 + threadIdx.x;
            if (idx < C2_ * C2_) {
                const int o  = idx / C2_;
                const int cc = idx - o * C2_;
                const int src = (cc < C_) ? (2 * cc) : (2 * (cc - C_) + 1);
                w1p[idx] = (bf16)w1[o * C2_ + src];
            }
            if (idx < OUT_ * C2_) w2b[idx] = (bf16)w2[idx];
            if (idx < 1152) stats[idx] = 0.f;   // p1s[384] p1q[384] p2s[192] p2q[192]
        }
        return;
    }
    __shared__ float T[32][65];
    const int b  = blockIdx.z;
    const int c0 = blockIdx.y * 32;
    const int n0 = blockIdx.x * 64;
    const int tid = threadIdx.x;
    {
        const int nl = tid & 63;
        const int cl = tid >> 6;
        #pragma unroll
        for (int r = 0; r < 8; ++r) {
            const int c = cl + r * 4;
            T[c][nl] = x[((size_t)b * C_ + (c0 + c)) * N_ + n0 + nl];
        }
    }
    __syncthreads();
    {
        const int cl = tid & 31;
        const int nl = tid >> 5;
        #pragma unroll
        for (int r = 0; r < 8; ++r) {
            const int n = nl + r * 8;
            xt[((size_t)b * N_ + n0 + n) * C_ + c0 + cl] = (bf16)T[cl][n];
        }
    }
}

// ---------------------------------------------------------------------------
// Feats (diff half): d[node][c] = max_k( xt[j_k][c] - xt[i_k][c] )
// grid M, block 192
__global__ __launch_bounds__(192) void k_feats(const bf16* __restrict__ xt,
                                               const int* __restrict__ eidx,
                                               bf16* __restrict__ dbuf) {
    const int node = blockIdx.x;
    const int b = node / N_;
    const int c = threadIdx.x;
    const int* e0 = eidx + (size_t)node * K_;
    const int* e1 = e0 + (size_t)M_ * K_;
    const bf16* xb = xt + (size_t)b * N_ * C_;
    float mx = -1e30f;
    #pragma unroll
    for (int k = 0; k < K_; ++k) {
        const int j = e0[k];
        const int i = e1[k];
        mx = fmaxf(mx, (float)xb[(size_t)j * C_ + c] - (float)xb[(size_t)i * C_ + c]);
    }
    dbuf[(size_t)node * C_ + c] = (bf16)mx;
}

// ---------------------------------------------------------------------------
// GEMM1: h1[m,o] = sum_c [X|D][m,c] * w1p[o,c] + b1[o] -> bf16, fused stats
// 128x128 tile, BK=64, swizzled LDS, 4 waves x (4x4) 16x16x32 frags
// grid (196, 3), block 256
__global__ __launch_bounds__(256) void k_gemm1(const bf16* __restrict__ X,
                                               const bf16* __restrict__ D,
                                               const bf16* __restrict__ Wp,
                                               const float* __restrict__ bias,
                                               bf16* __restrict__ H1,
                                               float* __restrict__ psum,
                                               float* __restrict__ psq) {
    __shared__ bf16 As[128 * 64];
    __shared__ bf16 Bs[128 * 64];
    const int tid  = threadIdx.x;
    const int lane = tid & 63;
    const int wv   = tid >> 6;
    const int l16  = lane & 15;
    const int quad = lane >> 4;
    const int m0   = blockIdx.x * 128;
    const int n0   = blockIdx.y * 128;
    const int wm   = (wv & 1) * 64;
    const int wn   = (wv >> 1) * 64;

    f32x4 acc[4][4] = {};

    for (int kk = 0; kk < C2_; kk += 64) {
        __syncthreads();
        const bf16* asrc = (kk < C_) ? X : D;
        const int   acol = (kk < C_) ? kk : (kk - C_);
        #pragma unroll
        for (int i = 0; i < 4; ++i) {
            const int qb = wv * 256 + i * 64;          // wave-uniform chunk base
            const int q  = qb + lane;
            const int r  = q >> 3;
            const int c8 = (q & 7) ^ (r & 7);          // global chunk for this slot
            gl_lds16(asrc + (size_t)(m0 + r) * C_ + acol + c8 * 8, &As[qb * 8]);
            gl_lds16(Wp   + (size_t)(n0 + r) * C2_ + kk  + c8 * 8, &Bs[qb * 8]);
        }
        __syncthreads();
        #pragma unroll
        for (int ks = 0; ks < 2; ++ks) {
            bf16x8 af[4], bfr[4];
            #pragma unroll
            for (int f = 0; f < 4; ++f) {
                af[f]  = *(const bf16x8*)&As[sw_off(wm + f * 16 + l16, ks * 4 + quad)];
                bfr[f] = *(const bf16x8*)&Bs[sw_off(wn + f * 16 + l16, ks * 4 + quad)];
            }
            #pragma unroll
            for (int mf = 0; mf < 4; ++mf)
                #pragma unroll
                for (int nf = 0; nf < 4; ++nf)
                    acc[mf][nf] = __builtin_amdgcn_mfma_f32_16x16x32_bf16(
                        af[mf], bfr[nf], acc[mf][nf], 0, 0, 0);
        }
    }

    #pragma unroll
    for (int nf = 0; nf < 4; ++nf) {
        const int col = n0 + wn + nf * 16 + l16;
        const float bv = bias[col];
        float s = 0.f, q = 0.f;
        #pragma unroll
        for (int mf = 0; mf < 4; ++mf) {
            #pragma unroll
            for (int r = 0; r < 4; ++r) {
                const float v = acc[mf][nf][r] + bv;
                s += v; q += v * v;
                H1[(size_t)(m0 + wm + mf * 16 + quad * 4 + r) * C2_ + col] = (bf16)v;
            }
        }
        s += __shfl_xor(s, 16); s += __shfl_xor(s, 32);
        q += __shfl_xor(q, 16); q += __shfl_xor(q, 32);
        if (quad == 0) { atomicAdd(&psum[col], s); atomicAdd(&psq[col], q); }
    }
}

// ---------------------------------------------------------------------------
// Activation: a1 = bf16(gelu(h1*sc + sh)).
// BN1 params computed ONCE PER BLOCK into LDS (384 rsqrt/block, coalesced
// broadcast loads), then streamed elementwise: 4 chunks of 8 per thread.
// grid 1176, block 256
__global__ __launch_bounds__(256) void k_act(const bf16* __restrict__ H1,
                                             const float* __restrict__ p1s,
                                             const float* __restrict__ p1q,
                                             const float* __restrict__ g,
                                             const float* __restrict__ beta,
                                             bf16* __restrict__ A1) {
    __shared__ float s_sc[C2_], s_sh[C2_];
    for (int c = threadIdx.x; c < C2_; c += 256) {
        const float mean = p1s[c] * (1.0f / (float)M_);
        const float var  = p1q[c] * (1.0f / (float)M_) - mean * mean;
        const float inv  = rsqrtf(var + EPS_);
        const float scl  = g[c] * inv;
        s_sc[c] = scl;
        s_sh[c] = beta[c] - mean * scl;
    }
    __syncthreads();
    #pragma unroll
    for (int t = 0; t < 4; ++t) {
        const size_t chunk = (size_t)blockIdx.x * 1024 + t * 256 + threadIdx.x;
        const size_t i8 = chunk * 8;
        const int c0 = (int)(i8 % C2_);
        const bf16x8 v = *(const bf16x8*)&H1[i8];
        const float4 sca = *(const float4*)&s_sc[c0];
        const float4 scb = *(const float4*)&s_sc[c0 + 4];
        const float4 sha = *(const float4*)&s_sh[c0];
        const float4 shb = *(const float4*)&s_sh[c0 + 4];
        const float scs[8] = {sca.x, sca.y, sca.z, sca.w, scb.x, scb.y, scb.z, scb.w};
        const float shs[8] = {sha.x, sha.y, sha.z, sha.w, shb.x, shb.y, shb.z, shb.w};
        bf16x8 o;
        #pragma unroll
        for (int j = 0; j < 8; ++j)
            o[j] = (bf16)gelu_f(fmaf((float)v[j], scs[j], shs[j]));
        *(bf16x8*)&A1[i8] = o;
    }
}

// ---------------------------------------------------------------------------
// GEMM2: h2[m,o] = sum_c a1[m,c]*w2[o,c] + b2[o] -> bf16, fused stats
// 128x64 tile, BK=64, swizzled LDS, 4 waves x (4x2) frags
// grid (196, 3), block 256
__global__ __launch_bounds__(256) void k_gemm2(const bf16* __restrict__ A1,
                                               const bf16* __restrict__ W2,
                                               const float* __restrict__ bias,
                                               bf16* __restrict__ H2,
                                               float* __restrict__ psum,
                                               float* __restrict__ psq) {
    __shared__ bf16 As[128 * 64];
    __shared__ bf16 Bs[64 * 64];
    const int tid  = threadIdx.x;
    const int lane = tid & 63;
    const int wv   = tid >> 6;
    const int l16  = lane & 15;
    const int quad = lane >> 4;
    const int m0   = blockIdx.x * 128;
    const int n0   = blockIdx.y * 64;
    const int wm   = (wv & 1) * 64;
    const int wn   = (wv >> 1) * 32;

    f32x4 acc[4][2] = {};

    for (int kk = 0; kk < C2_; kk += 64) {
        __syncthreads();
        #pragma unroll
        for (int i = 0; i < 4; ++i) {
            const int qb = wv * 256 + i * 64;
            const int q  = qb + lane;
            const int r  = q >> 3;
            const int c8 = (q & 7) ^ (r & 7);
            gl_lds16(A1 + (size_t)(m0 + r) * C2_ + kk + c8 * 8, &As[qb * 8]);
        }
        #pragma unroll
        for (int i = 0; i < 2; ++i) {
            const int qb = wv * 128 + i * 64;
            const int q  = qb + lane;
            const int r  = q >> 3;
            const int c8 = (q & 7) ^ (r & 7);
            gl_lds16(W2 + (size_t)(n0 + r) * C2_ + kk + c8 * 8, &Bs[qb * 8]);
        }
        __syncthreads();
        #pragma unroll
        for (int ks = 0; ks < 2; ++ks) {
            bf16x8 af[4], bfr[2];
            #pragma unroll
            for (int f = 0; f < 4; ++f)
                af[f] = *(const bf16x8*)&As[sw_off(wm + f * 16 + l16, ks * 4 + quad)];
            #pragma unroll
            for (int f = 0; f < 2; ++f)
                bfr[f] = *(const bf16x8*)&Bs[sw_off(wn + f * 16 + l16, ks * 4 + quad)];
            #pragma unroll
            for (int mf = 0; mf < 4; ++mf)
                #pragma unroll
                for (int nf = 0; nf < 2; ++nf)
                    acc[mf][nf] = __builtin_amdgcn_mfma_f32_16x16x32_bf16(
                        af[mf], bfr[nf], acc[mf][nf], 0, 0, 0);
        }
    }

    #pragma unroll
    for (int nf = 0; nf < 2; ++nf) {
        const int col = n0 + wn + nf * 16 + l16;
        const float bv = bias[col];
        float s = 0.f, q = 0.f;
        #pragma unroll
        for (int mf = 0; mf < 4; ++mf) {
            #pragma unroll
            for (int r = 0; r < 4; ++r) {
                const float v = acc[mf][nf][r] + bv;
                s += v; q += v * v;
                H2[(size_t)(m0 + wm + mf * 16 + quad * 4 + r) * OUT_ + col] = (bf16)v;
            }
        }
        s += __shfl_xor(s, 16); s += __shfl_xor(s, 32);
        q += __shfl_xor(q, 16); q += __shfl_xor(q, 32);
        if (quad == 0) { atomicAdd(&psum[col], s); atomicAdd(&psq[col], q); }
    }
}

// ---------------------------------------------------------------------------
// Output: BN2+GELU + transpose [M,OUT] bf16 -> [B,OUT,N] fp32
// BN2 params computed once per thread-column (one rsqrt per o-column).
// grid (N/64, OUT/32, B), block 256
__global__ __launch_bounds__(256) void k_out(const bf16* __restrict__ H2,
                                             const float* __restrict__ p2s,
                                             const float* __restrict__ p2q,
                                             const float* __restrict__ g,
                                             const float* __restrict__ beta,
                                             float* __restrict__ out) {
    __shared__ float T[64][33];
    const int b  = blockIdx.z;
    const int o0 = blockIdx.y * 32;
    const int n0 = blockIdx.x * 64;
    const int tid = threadIdx.x;
    {
        const int ol = tid & 31;
        const int nl = tid >> 5;
        const int o  = o0 + ol;
        const float mean  = p2s[o] * (1.0f / (float)M_);
        const float var   = p2q[o] * (1.0f / (float)M_) - mean * mean;
        const float inv   = rsqrtf(var + EPS_);
        const float scale = g[o] * inv;
        const float shift = beta[o] - mean * scale;
        #pragma unroll
        for (int r = 0; r < 8; ++r) {
            const int n = nl + r * 8;
            const float v = (float)H2[((size_t)b * N_ + n0 + n) * OUT_ + o];
            T[n][ol] = gelu_f(fmaf(v, scale, shift));
        }
    }
    __syncthreads();
    {
        const int nl = tid & 63;
        const int ol = tid >> 6;
        #pragma unroll
        for (int r = 0; r < 8; ++r) {
            const int o = ol + r * 4;
            out[((size_t)b * OUT_ + o0 + o) * N_ + n0 + nl] = T[nl][o];
        }
    }
}

// ---------------------------------------------------------------------------
extern "C" void kernel_launch(void* const* d_in, const int* in_sizes, int n_in,
                              void* d_out, int out_size, void* d_ws, size_t ws_size,
                              hipStream_t stream) {
    const float* x     = (const float*)d_in[0];
    const int*   eidx  = (const int*)  d_in[1];
    const float* w1    = (const float*)d_in[2];
    const float* b1    = (const float*)d_in[3];
    const float* g1    = (const float*)d_in[4];
    const float* beta1 = (const float*)d_in[5];
    const float* w2    = (const float*)d_in[6];
    const float* b2    = (const float*)d_in[7];
    const float* g2    = (const float*)d_in[8];
    const float* beta2 = (const float*)d_in[9];
    float* out = (float*)d_out;

    char* ws = (char*)d_ws;
    size_t off = 0;
    bf16*  xt    = (bf16*)(ws + off); off += (size_t)M_ * C_  * sizeof(bf16);
    bf16*  dbuf  = (bf16*)(ws + off); off += (size_t)M_ * C_  * sizeof(bf16);
    bf16*  h1    = (bf16*)(ws + off); off += (size_t)M_ * C2_ * sizeof(bf16);
    bf16*  a1    = (bf16*)(ws + off); off += (size_t)M_ * C2_ * sizeof(bf16);
    bf16*  h2    = (bf16*)(ws + off); off += (size_t)M_ * OUT_ * sizeof(bf16);
    bf16*  w1p   = (bf16*)(ws + off); off += (size_t)C2_ * C2_ * sizeof(bf16);
    bf16*  w2b   = (bf16*)(ws + off); off += (size_t)OUT_ * C2_ * sizeof(bf16);
    float* stats = (float*)(ws + off); off += 1152 * sizeof(float);
    float* p1s = stats;        // 384
    float* p1q = stats + 384;  // 384
    float* p2s = stats + 768;  // 192
    float* p2q = stats + 960;  // 192

    k_pre<<<dim3(N_ / 64, C_ / 32, B_ + 1), 256, 0, stream>>>(x, xt, w1, w2, w1p, w2b, stats);
    k_feats<<<M_, 192, 0, stream>>>(xt, eidx, dbuf);
    k_gemm1<<<dim3(M_ / 128, C2_ / 128), 256, 0, stream>>>(xt, dbuf, w1p, b1, h1, p1s, p1q);
    k_act<<<1176, 256, 0, stream>>>(h1, p1s, p1q, g1, beta1, a1);
    k_gemm2<<<dim3(M_ / 128, OUT_ / 64), 256, 0, stream>>>(a1, w2b, b2, h2, p2s, p2q);
    k_out<<<dim3(N_ / 64, OUT_ / 32, B_), 256, 0, stream>>>(h2, p2s, p2q, g2, beta2, out);
}